// Round 7
// baseline (5848.619 us; speedup 1.0000x reference)
//
#include <hip/hip_runtime.h>
#include <math.h>

#define N      100   // nodes per problem
#define D      128   // embedding dim = H*DKH
#define KL     10    // prefix length
#define S0     90    // unvisited slots (fixed)
#define STEPS  90
#define LDK    132   // LDS row stride (floats); odd float4 count
#define NT     512

#define WS_PER_KIND 12800            // 100*128 floats
#define WS_PER_B    51200            // 4 kinds

__device__ __forceinline__ float dot4(float4 a, float4 b) {
  return a.x*b.x + a.y*b.y + a.z*b.z + a.w*b.w;
}
__device__ __forceinline__ void fma4(float4& acc, float a, float4 v) {
  acc.x += a*v.x; acc.y += a*v.y; acc.z += a*v.z; acc.w += a*v.w;
}

// ===================== Kernel 1: batched setup GEMM =====================
// ws[b][kind][node][col] = (enc[b] @ W_kind)[node][col], bitwise-identical
// FP order to the in-kernel cc() passes: per 16-chunk a0..a3 partials,
// acc += (a0+a1)+(a2+a3).
// kinds: 0=Wk (col-major idx), 1=Wv, 2=Wcomb (row-major idx), 3=Wq_last.
__global__ __launch_bounds__(256)
void setup_gemm(const float* __restrict__ enc,
                const float* __restrict__ Wk,
                const float* __restrict__ Wv,
                const float* __restrict__ Wcomb,
                const float* __restrict__ Wq_last,
                float* __restrict__ ws) {
  const int blk  = blockIdx.x;
  const int rem  = blk % 52;
  const int b    = blk / 52;
  const int kind = rem / 13;
  const int tile = rem % 13;          // 13 tiles x 8 rows >= 100
  const int col  = threadIdx.x & 127;
  const int rh   = threadIdx.x >> 7;  // 0/1, wave-uniform
  const float* W = (kind==0) ? Wk : (kind==1) ? Wv : (kind==2) ? Wcomb : Wq_last;
  const bool rowMajor = (kind == 2);
  const float* encB = enc + (size_t)b*N*D;

  int rows[4];
  float acc[4];
  #pragma unroll
  for (int j = 0; j < 4; ++j) { rows[j] = tile*8 + rh + 2*j; acc[j] = 0.f; }

  for (int dd = 0; dd < D; dd += 16) {
    float w[16];
    #pragma unroll
    for (int t = 0; t < 16; ++t)
      w[t] = rowMajor ? W[col*D + dd + t] : W[(dd+t)*D + col];
    #pragma unroll
    for (int j = 0; j < 4; ++j) {
      if (rows[j] < N) {
        const float* er = encB + (size_t)rows[j]*D + dd;   // wave-uniform row
        float a0=0,a1=0,a2=0,a3=0;
        #pragma unroll
        for (int t = 0; t < 16; t += 4) {
          a0 += er[t]*w[t];   a1 += er[t+1]*w[t+1];
          a2 += er[t+2]*w[t+2]; a3 += er[t+3]*w[t+3];
        }
        acc[j] += (a0+a1)+(a2+a3);
      }
    }
  }
  float* o = ws + ((size_t)b*4 + kind)*WS_PER_KIND;
  #pragma unroll
  for (int j = 0; j < 4; ++j)
    if (rows[j] < N) o[rows[j]*D + col] = acc[j];
}

// ===================== shared decode body helpers =====================
// Gather rows 0..89 (nodes slotNode[r]) of one ws kind into sCE, float4.
__device__ __forceinline__ void stage90(const float* __restrict__ wsKind,
                                        const int* __restrict__ slotNode,
                                        float* __restrict__ sCE, int tid) {
  const int c4  = (tid & 31) * 4;    // col (float index)
  const int grp = tid >> 5;          // 0..15
  #pragma unroll
  for (int ii = 0; ii < 6; ++ii) {
    int r = grp + 16*ii;             // 0..95
    if (r < S0) {
      int nd = slotNode[r];
      *(float4*)&sCE[r*LDK + c4] = *(const float4*)&wsKind[(size_t)nd*D + c4];
    }
  }
}

// Rows [base, base+cnt) of E@W -> stage[row*LDK+col].  (fallback path only)
template<int RPT>
__device__ __forceinline__ void cc(const float* __restrict__ encB,
                                   const float* __restrict__ W,
                                   bool wRowMajor, int base, int cnt,
                                   const int* __restrict__ slotNode,
                                   float* __restrict__ stage, int tid) {
  const int col = tid & 127;
  const int grp = tid >> 7;
  float acc[RPT];
  int   nd [RPT];
  #pragma unroll
  for (int ii = 0; ii < RPT; ++ii) {
    acc[ii] = 0.f;
    int r = grp + 4*ii;
    nd[ii] = (r < cnt) ? __builtin_amdgcn_readfirstlane(slotNode[base + r]) : 0;
  }
  for (int dd = 0; dd < D; dd += 16) {
    float w[16];
    #pragma unroll
    for (int t = 0; t < 16; ++t)
      w[t] = wRowMajor ? W[col*D + dd + t] : W[(dd+t)*D + col];
    #pragma unroll
    for (int ii = 0; ii < RPT; ++ii) {
      int r = grp + 4*ii;
      if (r < cnt) {
        const float* er = encB + (size_t)nd[ii]*D + dd;
        float a0=0,a1=0,a2=0,a3=0;
        #pragma unroll
        for (int t = 0; t < 16; t += 4) {
          a0 += er[t]*w[t];   a1 += er[t+1]*w[t+1];
          a2 += er[t+2]*w[t+2]; a3 += er[t+3]*w[t+3];
        }
        acc[ii] += (a0+a1)+(a2+a3);
      }
    }
  }
  #pragma unroll
  for (int ii = 0; ii < RPT; ++ii) {
    int r = grp + 4*ii;
    if (r < cnt) stage[(base + r)*LDK + col] = acc[ii];
  }
}

// The decode loop + everything after fragment setup, shared by both kernels.
// Template over nothing — plain inline function; all state passed in.
struct DecodeState {
  float4 ka0,ka1,ka2,ka3, kb0,kb1,kb2,kb3;
  float4 v0,v1,v2,v3,v4,v5;
  float  qp[23];
};

__device__ __forceinline__ void decode_loop(DecodeState& st,
                                            float* sq, float* sMh, float* sSum,
                                            float* sCE, int* sSlotNode,
                                            unsigned long long* sPacked,
                                            int tid, int b,
                                            int* __restrict__ out) {
  const int h = tid >> 6, l = tid & 63;
  const int qcol = (h << 4) | (l & 15);
  const int qrg  = l >> 4;
  const int cQuad = tid >> 4;
  const int cStrm = tid & 15;
  const int ch    = cQuad >> 2;
  const int di  = tid >> 2;
  const int dkc = tid & 3;
  float visA = 0.f, visB = 0.f, visD = 0.f;

  for (int step = 0; step < STEPS; ++step) {
    // B: scores vs register K; exp; per-head partition sum (wave-local)
    float x0, x1;
    {
      const float4 q0 = *(const float4*)&sq[h*16 + 0];
      const float4 q1 = *(const float4*)&sq[h*16 + 4];
      const float4 q2 = *(const float4*)&sq[h*16 + 8];
      const float4 q3 = *(const float4*)&sq[h*16 + 12];
      float s0 = dot4(q0,st.ka0)+dot4(q1,st.ka1)+dot4(q2,st.ka2)+dot4(q3,st.ka3);
      x0 = expf(s0*0.25f + visA);
      x1 = 0.f;
      if (l < 26) {
        float s1 = dot4(q0,st.kb0)+dot4(q1,st.kb1)+dot4(q2,st.kb2)+dot4(q3,st.kb3);
        x1 = expf(s1*0.25f + visB);
      }
      float loc = x0 + x1;
      #pragma unroll
      for (int off = 32; off; off >>= 1) loc += __shfl_xor(loc, off);
      if (l == 0) sSum[h] = loc;
    }

    // C: mh from register V; att pulled from B's registers via shfl
    {
      const float a0 = __shfl(x0, cStrm);
      const float a1 = __shfl(x0, cStrm + 16);
      const float a2 = __shfl(x0, cStrm + 32);
      const float a3 = __shfl(x0, cStrm + 48);
      const float a4 = __shfl(x1, cStrm);
      const float a5 = __shfl(x1, cStrm + 16);
      float4 acc = make_float4(0.f,0.f,0.f,0.f);
      fma4(acc, a0, st.v0);
      fma4(acc, a1, st.v1);
      fma4(acc, a2, st.v2);
      fma4(acc, a3, st.v3);
      fma4(acc, a4, st.v4);
      fma4(acc, a5, st.v5);
      #pragma unroll
      for (int off = 1; off < 16; off <<= 1) {
        acc.x += __shfl_xor(acc.x, off);
        acc.y += __shfl_xor(acc.y, off);
        acc.z += __shfl_xor(acc.z, off);
        acc.w += __shfl_xor(acc.w, off);
      }
      if (cStrm == 0) {
        const float r = 1.0f / sSum[ch];
        float4 o; o.x=acc.x*r; o.y=acc.y*r; o.z=acc.z*r; o.w=acc.w*r;
        *(float4*)&sMh[cQuad*4] = o;
      }
    }
    __syncthreads();                               // BAR1: sMh complete

    if (tid == NT-1) sPacked[(step+1)&1] = 0ull;

    // D: sc[i] = mh . CE_lds[i]; argmax -> packed atomicMax
    if (tid < 384) {
      float a = 0.f;
      #pragma unroll
      for (int j = 0; j < 8; ++j) {
        const float4 ce = *(const float4*)&sCE[di*LDK + dkc*32 + j*4];
        const float4 mh = *(const float4*)&sMh[dkc*32 + j*4];
        a += dot4(ce, mh);
      }
      a += __shfl_xor(a, 1);
      a += __shfl_xor(a, 2);
      float val = (di < S0) ? a + visD : -INFINITY;
      int   idx = (di < S0) ? di : 127;
      #pragma unroll
      for (int off = 4; off <= 32; off <<= 1) {
        float ov = __shfl_xor(val, off);
        int   oi = __shfl_xor(idx, off);
        if (ov > val || (ov == val && oi < idx)) { val = ov; idx = oi; }
      }
      if (l == 0) {
        unsigned s = __float_as_uint(val);
        s = (s & 0x80000000u) ? ~s : (s | 0x80000000u);
        unsigned long long pk = ((unsigned long long)s << 32)
                              | (unsigned long long)(unsigned)(127 - idx);
        atomicMax(&sPacked[step&1], pk);
      }
    }
    __syncthreads();                               // BAR2: winner complete

    // A: read winner; write out; update vis; publish next q row (wave-local)
    {
      const unsigned long long u = sPacked[step & 1];
      const int idx = __builtin_amdgcn_readfirstlane(127 - (int)(u & 0xFFull));
      if (tid == 0) out[(size_t)b*N + KL + step] = sSlotNode[idx];
      if (idx == l)      visA = -INFINITY;
      if (idx == l + 64) visB = -INFINITY;
      if (idx == di)     visD = -INFINITY;
      const int want = idx >> 2;
      float qv = st.qp[0];
      #pragma unroll
      for (int ii = 1; ii < 23; ++ii) qv = (want == ii) ? st.qp[ii] : qv;
      if (qrg == (idx & 3)) sq[qcol] = qv;
    }
  }
}

// ===================== Kernel 2: decode (ws-staged) =====================
__global__ __launch_bounds__(NT, 4)
void policy_kernel_split(const float* __restrict__ enc,
                         const float* __restrict__ Wq_first,
                         const int*   __restrict__ prefix,
                         const float* __restrict__ ws,
                         int*         __restrict__ out) {
  __shared__ __align__(16) float sCE[S0*LDK];
  __shared__ __align__(16) float sq[D];
  __shared__ __align__(16) float sMh[D];
  __shared__ float sSum[8];
  __shared__ int   sSlotNode[96];
  __shared__ unsigned long long sPacked[2];
  __shared__ int   sLast0;

  const int tid = threadIdx.x;
  const int b   = blockIdx.x;
  const float* encB = enc + (size_t)b*N*D;
  const float* wsB  = ws + (size_t)b*WS_PER_B;
  const float* wsK  = wsB;
  const float* wsV  = wsB + WS_PER_KIND;
  const float* wsCE = wsB + 2*WS_PER_KIND;
  const float* wsQ  = wsB + 3*WS_PER_KIND;

  // ---- init ----
  if (tid < KL) out[(size_t)b*N + tid] = prefix[b*KL + tid];
  if (tid == 0) {
    unsigned vis[4] = {0u,0u,0u,0u};
    const int* pr = prefix + b*KL;
    for (int j = 0; j < KL; ++j) { int n = pr[j]; vis[n>>5] |= 1u << (n&31); }
    int cnt = 0;
    for (int n = 0; n < N; ++n)
      if (!((vis[n>>5] >> (n&31)) & 1u)) sSlotNode[cnt++] = n;
    sLast0 = pr[KL-1];
    sPacked[0] = 0ull; sPacked[1] = 0ull;
  }
  __syncthreads();

  // ---- q1 = enc[last0] @ Wq_first -> sMh ----
  if (tid < D) {
    const int last0 = sLast0;
    const float* er = encB + (size_t)last0*D;
    float a0=0,a1=0,a2=0,a3=0;
    #pragma unroll
    for (int d = 0; d < D; d += 4) {
      a0 += er[d]  *Wq_first[d*D     + tid];
      a1 += er[d+1]*Wq_first[(d+1)*D + tid];
      a2 += er[d+2]*Wq_first[(d+2)*D + tid];
      a3 += er[d+3]*Wq_first[(d+3)*D + tid];
    }
    sMh[tid] = (a0+a1)+(a2+a3);
  }
  __syncthreads();

  const int h = tid >> 6, l = tid & 63;
  const int qcol = (h << 4) | (l & 15);
  const int qrg  = l >> 4;
  DecodeState st;

  // ---- Q stage from ws + initial sq ----
  stage90(wsQ, sSlotNode, sCE, tid);
  if (tid < D) sq[tid] = wsQ[(size_t)sLast0*D + tid] + sMh[tid];
  __syncthreads();

  // ---- qp readback (per-head layout) ----
  {
    const float q1c = sMh[qcol];
    #pragma unroll
    for (int ii = 0; ii < 23; ++ii) {
      int r = qrg + 4*ii;
      st.qp[ii] = (r < S0) ? (sCE[r*LDK + qcol] + q1c) : 0.f;
    }
  }
  __syncthreads();

  // ---- K stage + frag reads ----
  stage90(wsK, sSlotNode, sCE, tid);
  __syncthreads();
  {
    const float* p = &sCE[l*LDK + h*16];
    st.ka0 = *(const float4*)(p+0);  st.ka1 = *(const float4*)(p+4);
    st.ka2 = *(const float4*)(p+8);  st.ka3 = *(const float4*)(p+12);
  }
  if (l < 26) {
    const float* p = &sCE[(64+l)*LDK + h*16];
    st.kb0 = *(const float4*)(p+0);  st.kb1 = *(const float4*)(p+4);
    st.kb2 = *(const float4*)(p+8);  st.kb3 = *(const float4*)(p+12);
  } else {
    st.kb0=st.kb1=st.kb2=st.kb3 = make_float4(0.f,0.f,0.f,0.f);
  }
  __syncthreads();

  // ---- V stage + frag reads ----
  const int cQuad = tid >> 4;
  const int cStrm = tid & 15;
  stage90(wsV, sSlotNode, sCE, tid);
  __syncthreads();
  st.v0 = *(const float4*)&sCE[(cStrm     )*LDK + cQuad*4];
  st.v1 = *(const float4*)&sCE[(cStrm + 16)*LDK + cQuad*4];
  st.v2 = *(const float4*)&sCE[(cStrm + 32)*LDK + cQuad*4];
  st.v3 = *(const float4*)&sCE[(cStrm + 48)*LDK + cQuad*4];
  st.v4 = *(const float4*)&sCE[(cStrm + 64)*LDK + cQuad*4];
  st.v5 = (cStrm < 10) ? *(const float4*)&sCE[(cStrm + 80)*LDK + cQuad*4]
                       : make_float4(0.f,0.f,0.f,0.f);
  __syncthreads();

  // ---- CE stage (final home) ----
  stage90(wsCE, sSlotNode, sCE, tid);
  __syncthreads();

  decode_loop(st, sq, sMh, sSum, sCE, sSlotNode, sPacked, tid, b, out);
}

// ===================== Fallback: fused kernel (round-6) =====================
__global__ __launch_bounds__(NT, 4)
void policy_kernel(const float* __restrict__ enc,
                   const float* __restrict__ Wq_first,
                   const float* __restrict__ Wq_last,
                   const float* __restrict__ Wk,
                   const float* __restrict__ Wv,
                   const float* __restrict__ Wcomb,
                   const int*   __restrict__ prefix,
                   int*         __restrict__ out) {
  __shared__ __align__(16) float sCE[S0*LDK];
  __shared__ __align__(16) float sq[D];
  __shared__ __align__(16) float sMh[D];
  __shared__ float sSum[8];
  __shared__ int   sSlotNode[96];
  __shared__ unsigned long long sPacked[2];
  __shared__ int   sLast0;

  const int tid = threadIdx.x;
  const int b   = blockIdx.x;
  const float* encB = enc + (size_t)b*N*D;

  if (tid < KL) out[(size_t)b*N + tid] = prefix[b*KL + tid];
  if (tid == 0) {
    unsigned vis[4] = {0u,0u,0u,0u};
    const int* pr = prefix + b*KL;
    for (int j = 0; j < KL; ++j) { int n = pr[j]; vis[n>>5] |= 1u << (n&31); }
    int cnt = 0;
    for (int n = 0; n < N; ++n)
      if (!((vis[n>>5] >> (n&31)) & 1u)) sSlotNode[cnt++] = n;
    sLast0 = pr[KL-1];
    sPacked[0] = 0ull; sPacked[1] = 0ull;
  }
  __syncthreads();

  if (tid < D) {
    const int last0 = sLast0;
    const float* er = encB + (size_t)last0*D;
    float a0=0,a1=0,a2=0,a3=0;
    #pragma unroll
    for (int d = 0; d < D; d += 4) {
      a0 += er[d]  *Wq_first[d*D     + tid];
      a1 += er[d+1]*Wq_first[(d+1)*D + tid];
      a2 += er[d+2]*Wq_first[(d+2)*D + tid];
      a3 += er[d+3]*Wq_first[(d+3)*D + tid];
    }
    sMh[tid] = (a0+a1)+(a2+a3);
  }
  __syncthreads();

  const int h = tid >> 6, l = tid & 63;
  const int qcol = (h << 4) | (l & 15);
  const int qrg  = l >> 4;
  DecodeState st;

  {
    const int col = tid & 127;
    const int grp = tid >> 7;
    float acc[23]; int nd[23];
    #pragma unroll
    for (int ii = 0; ii < 23; ++ii) {
      int r = grp + 4*ii;
      acc[ii] = 0.f;
      nd[ii] = (r < S0) ? __builtin_amdgcn_readfirstlane(sSlotNode[r])
                        : ((r == S0) ? sLast0 : 0);
    }
    for (int dd = 0; dd < D; dd += 16) {
      float w[16];
      #pragma unroll
      for (int t = 0; t < 16; ++t) w[t] = Wq_last[(dd+t)*D + col];
      #pragma unroll
      for (int ii = 0; ii < 23; ++ii) {
        int r = grp + 4*ii;
        if (r <= S0) {
          const float* er = encB + (size_t)nd[ii]*D + dd;
          float a0=0,a1=0,a2=0,a3=0;
          #pragma unroll
          for (int t = 0; t < 16; t += 4) {
            a0 += er[t]*w[t];   a1 += er[t+1]*w[t+1];
            a2 += er[t+2]*w[t+2]; a3 += er[t+3]*w[t+3];
          }
          acc[ii] += (a0+a1)+(a2+a3);
        }
      }
    }
    #pragma unroll
    for (int ii = 0; ii < 23; ++ii) {
      int r = grp + 4*ii;
      if (r < S0)       sCE[r*LDK + col] = acc[ii];
      else if (r == S0) sq[col] = acc[ii] + sMh[col];
    }
  }
  __syncthreads();

  {
    const float q1c = sMh[qcol];
    #pragma unroll
    for (int ii = 0; ii < 23; ++ii) {
      int r = qrg + 4*ii;
      st.qp[ii] = (r < S0) ? (sCE[r*LDK + qcol] + q1c) : 0.f;
    }
  }
  __syncthreads();

  cc<23>(encB, Wk, false, 0, S0, sSlotNode, sCE, tid);
  __syncthreads();
  {
    const float* p = &sCE[l*LDK + h*16];
    st.ka0 = *(const float4*)(p+0);  st.ka1 = *(const float4*)(p+4);
    st.ka2 = *(const float4*)(p+8);  st.ka3 = *(const float4*)(p+12);
  }
  if (l < 26) {
    const float* p = &sCE[(64+l)*LDK + h*16];
    st.kb0 = *(const float4*)(p+0);  st.kb1 = *(const float4*)(p+4);
    st.kb2 = *(const float4*)(p+8);  st.kb3 = *(const float4*)(p+12);
  } else {
    st.kb0=st.kb1=st.kb2=st.kb3 = make_float4(0.f,0.f,0.f,0.f);
  }
  __syncthreads();

  const int cQuad = tid >> 4;
  const int cStrm = tid & 15;
  cc<12>(encB, Wv, false,  0, 48, sSlotNode, sCE, tid);
  cc<12>(encB, Wv, false, 48, 42, sSlotNode, sCE, tid);
  __syncthreads();
  st.v0 = *(const float4*)&sCE[(cStrm     )*LDK + cQuad*4];
  st.v1 = *(const float4*)&sCE[(cStrm + 16)*LDK + cQuad*4];
  st.v2 = *(const float4*)&sCE[(cStrm + 32)*LDK + cQuad*4];
  st.v3 = *(const float4*)&sCE[(cStrm + 48)*LDK + cQuad*4];
  st.v4 = *(const float4*)&sCE[(cStrm + 64)*LDK + cQuad*4];
  st.v5 = (cStrm < 10) ? *(const float4*)&sCE[(cStrm + 80)*LDK + cQuad*4]
                       : make_float4(0.f,0.f,0.f,0.f);
  __syncthreads();

  cc<6>(encB, Wcomb, true,  0, 24, sSlotNode, sCE, tid);
  cc<6>(encB, Wcomb, true, 24, 24, sSlotNode, sCE, tid);
  cc<6>(encB, Wcomb, true, 48, 24, sSlotNode, sCE, tid);
  cc<6>(encB, Wcomb, true, 72, 18, sSlotNode, sCE, tid);
  __syncthreads();

  decode_loop(st, sq, sMh, sSum, sCE, sSlotNode, sPacked, tid, b, out);
}

extern "C" void kernel_launch(void* const* d_in, const int* in_sizes, int n_in,
                              void* d_out, int out_size, void* d_ws, size_t ws_size,
                              hipStream_t stream) {
  // inputs: 0 problems (unused), 1 encoded_nodes f32, 2 Wq_first, 3 Wq_last,
  //         4 Wk, 5 Wv, 6 Wcomb, 7 prefix i32
  const float* enc      = (const float*)d_in[1];
  const float* Wq_first = (const float*)d_in[2];
  const float* Wq_last  = (const float*)d_in[3];
  const float* Wk       = (const float*)d_in[4];
  const float* Wv       = (const float*)d_in[5];
  const float* Wcomb    = (const float*)d_in[6];
  const int*   prefix   = (const int*)d_in[7];
  const int batch = in_sizes[7] / KL;   // 2048

  const size_t need = (size_t)batch * WS_PER_B * sizeof(float);  // ~420 MB
  if (d_ws && ws_size >= need) {
    setup_gemm<<<batch*52, 256, 0, stream>>>(enc, Wk, Wv, Wcomb, Wq_last,
                                             (float*)d_ws);
    policy_kernel_split<<<batch, NT, 0, stream>>>(enc, Wq_first, prefix,
                                                  (const float*)d_ws,
                                                  (int*)d_out);
  } else {
    policy_kernel<<<batch, NT, 0, stream>>>(enc, Wq_first, Wq_last, Wk, Wv,
                                            Wcomb, prefix, (int*)d_out);
  }
}

// Round 10
// 2279.953 us; speedup vs baseline: 2.5652x; 2.5652x over previous
//
#include <hip/hip_runtime.h>
#include <math.h>

#define N      100   // nodes per problem
#define D      128   // embedding dim = H*DKH
#define KL     10    // prefix length
#define S0     90    // unvisited slots (fixed)
#define STEPS  90
#define LDK    132   // LDS row stride (floats); odd float4 count
#define NT     512

__device__ __forceinline__ float dot4(float4 a, float4 b) {
  return a.x*b.x + a.y*b.y + a.z*b.z + a.w*b.w;
}
__device__ __forceinline__ void fma4(float4& acc, float a, float4 v) {
  acc.x += a*v.x; acc.y += a*v.y; acc.z += a*v.z; acc.w += a*v.w;
}

// Rows [base, base+cnt) of E@W (col-major W) or Wcomb (row-major) -> stage[row*LDK+col].
// grp = tid>>7 is WAVE-UNIFORM -> nd[] in SGPRs, enc row loads are scalar loads.
template<int RPT>
__device__ __forceinline__ void cc(const float* __restrict__ encB,
                                   const float* __restrict__ W,
                                   bool wRowMajor, int base, int cnt,
                                   const int* __restrict__ slotNode,
                                   float* __restrict__ stage, int tid) {
  const int col = tid & 127;
  const int grp = tid >> 7;
  float acc[RPT];
  int   nd [RPT];
  #pragma unroll
  for (int ii = 0; ii < RPT; ++ii) {
    acc[ii] = 0.f;
    int r = grp + 4*ii;
    nd[ii] = (r < cnt) ? __builtin_amdgcn_readfirstlane(slotNode[base + r]) : 0;
  }
  for (int dd = 0; dd < D; dd += 16) {
    float w[16];
    #pragma unroll
    for (int t = 0; t < 16; ++t)
      w[t] = wRowMajor ? W[col*D + dd + t] : W[(dd+t)*D + col];
    #pragma unroll
    for (int ii = 0; ii < RPT; ++ii) {
      int r = grp + 4*ii;
      if (r < cnt) {
        const float* er = encB + (size_t)nd[ii]*D + dd;
        float a0=0,a1=0,a2=0,a3=0;
        #pragma unroll
        for (int t = 0; t < 16; t += 4) {
          a0 += er[t]*w[t];   a1 += er[t+1]*w[t+1];
          a2 += er[t+2]*w[t+2]; a3 += er[t+3]*w[t+3];
        }
        acc[ii] += (a0+a1)+(a2+a3);
      }
    }
  }
  #pragma unroll
  for (int ii = 0; ii < RPT; ++ii) {
    int r = grp + 4*ii;
    if (r < cnt) stage[(base + r)*LDK + col] = acc[ii];
  }
}

__global__ __launch_bounds__(NT, 4)   // 4 waves/EU -> <=128 VGPR
void policy_kernel(const float* __restrict__ enc,
                   const float* __restrict__ Wq_first,
                   const float* __restrict__ Wq_last,
                   const float* __restrict__ Wk,
                   const float* __restrict__ Wv,
                   const float* __restrict__ Wcomb,
                   const int*   __restrict__ prefix,
                   int*         __restrict__ out) {
  // ---- LDS < 48 KiB ----
  __shared__ __align__(16) float sCE[S0*LDK];  // 47.5 KB: staging for q,K,V; final CE home
  __shared__ __align__(16) float sq[D];        // current q row
  __shared__ __align__(16) float sMh[D];       // q1 scratch (plain idx), then normalized
                                               // mh in SWIZZLED layout (see decode)
  __shared__ int   sSlotNode[96];
  __shared__ unsigned long long sPacked[2];    // double-buffered argmax
  __shared__ int   sLast0;

  const int tid = threadIdx.x;
  const int b   = blockIdx.x;
  const float* encB = enc + (size_t)b*N*D;

  // ---- init ----
  if (tid < KL) out[(size_t)b*N + tid] = prefix[b*KL + tid];
  if (tid == 0) {
    unsigned vis[4] = {0u,0u,0u,0u};
    const int* pr = prefix + b*KL;
    for (int j = 0; j < KL; ++j) { int n = pr[j]; vis[n>>5] |= 1u << (n&31); }
    int cnt = 0;
    for (int n = 0; n < N; ++n)
      if (!((vis[n>>5] >> (n&31)) & 1u)) sSlotNode[cnt++] = n;
    sLast0 = pr[KL-1];
    sPacked[0] = 0ull; sPacked[1] = 0ull;
  }
  __syncthreads();

  // ---- q1 = enc[last0] @ Wq_first -> sMh (scratch, plain indexing) ----
  if (tid < D) {
    const int last0 = sLast0;
    const float* er = encB + (size_t)last0*D;
    float a0=0,a1=0,a2=0,a3=0;
    #pragma unroll
    for (int d = 0; d < D; d += 4) {
      a0 += er[d]  *Wq_first[d*D     + tid];
      a1 += er[d+1]*Wq_first[(d+1)*D + tid];
      a2 += er[d+2]*Wq_first[(d+2)*D + tid];
      a3 += er[d+3]*Wq_first[(d+3)*D + tid];
    }
    sMh[tid] = (a0+a1)+(a2+a3);
  }
  __syncthreads();

  const int h = tid >> 6, l = tid & 63;

  // ---- q build in WAVE-UNIFORM layout (SGPR nd, scalar enc loads).
  //      Rows 0..89 -> sCE (no q1 yet); row 90 (last0) -> sq with q1 added. ----
  {
    const int col = tid & 127;
    const int grp = tid >> 7;     // wave-uniform
    float acc[23]; int nd[23];
    #pragma unroll
    for (int ii = 0; ii < 23; ++ii) {
      int r = grp + 4*ii;
      acc[ii] = 0.f;
      nd[ii] = (r < S0) ? __builtin_amdgcn_readfirstlane(sSlotNode[r])
                        : ((r == S0) ? sLast0 : 0);
    }
    for (int dd = 0; dd < D; dd += 16) {
      float w[16];
      #pragma unroll
      for (int t = 0; t < 16; ++t) w[t] = Wq_last[(dd+t)*D + col];
      #pragma unroll
      for (int ii = 0; ii < 23; ++ii) {
        int r = grp + 4*ii;
        if (r <= S0) {
          const float* er = encB + (size_t)nd[ii]*D + dd;
          float a0=0,a1=0,a2=0,a3=0;
          #pragma unroll
          for (int t = 0; t < 16; t += 4) {
            a0 += er[t]*w[t];   a1 += er[t+1]*w[t+1];
            a2 += er[t+2]*w[t+2]; a3 += er[t+3]*w[t+3];
          }
          acc[ii] += (a0+a1)+(a2+a3);
        }
      }
    }
    #pragma unroll
    for (int ii = 0; ii < 23; ++ii) {
      int r = grp + 4*ii;
      if (r < S0)       sCE[r*LDK + col] = acc[ii];
      else if (r == S0) sq[col] = acc[ii] + sMh[col];   // initial q row (last0)
    }
  }
  __syncthreads();

  // ---- one-time transpose read-back into PER-HEAD qp layout:
  //      wave h, lane l holds qp[ii] = q[(l>>4)+4*ii][16h+(l&15)]
  //      -> winner-row publish in phase A is wave-local (no barrier E->B).
  const int qcol = (h << 4) | (l & 15);
  const int qrg  = l >> 4;
  float qp[23];
  {
    const float q1c = sMh[qcol];
    #pragma unroll
    for (int ii = 0; ii < 23; ++ii) {
      int r = qrg + 4*ii;
      qp[ii] = (r < S0) ? (sCE[r*LDK + qcol] + q1c) : 0.f;
    }
  }
  __syncthreads();   // qp read complete before K pass overwrites sCE

  // ---- K pass: stage all 90 rows, load per-lane fragments ----
  cc<23>(encB, Wk, false, 0, S0, sSlotNode, sCE, tid);
  __syncthreads();
  float4 ka0,ka1,ka2,ka3, kb0,kb1,kb2,kb3;
  {
    const float* p = &sCE[l*LDK + h*16];
    ka0 = *(const float4*)(p+0);  ka1 = *(const float4*)(p+4);
    ka2 = *(const float4*)(p+8);  ka3 = *(const float4*)(p+12);
  }
  if (l < 26) {
    const float* p = &sCE[(64+l)*LDK + h*16];
    kb0 = *(const float4*)(p+0);  kb1 = *(const float4*)(p+4);
    kb2 = *(const float4*)(p+8);  kb3 = *(const float4*)(p+12);
  } else {
    kb0=kb1=kb2=kb3 = make_float4(0.f,0.f,0.f,0.f);
  }
  __syncthreads();

  // ---- V pass: stage, load per-thread fragments ----
  const int cQuad = tid >> 4;   // 0..31 (output quad)
  const int cStrm = tid & 15;   // slot stream
  cc<12>(encB, Wv, false,  0, 48, sSlotNode, sCE, tid);
  cc<12>(encB, Wv, false, 48, 42, sSlotNode, sCE, tid);
  __syncthreads();
  float4 v0,v1,v2,v3,v4,v5;
  v0 = *(const float4*)&sCE[(cStrm     )*LDK + cQuad*4];
  v1 = *(const float4*)&sCE[(cStrm + 16)*LDK + cQuad*4];
  v2 = *(const float4*)&sCE[(cStrm + 32)*LDK + cQuad*4];
  v3 = *(const float4*)&sCE[(cStrm + 48)*LDK + cQuad*4];
  v4 = *(const float4*)&sCE[(cStrm + 64)*LDK + cQuad*4];
  v5 = (cStrm < 10) ? *(const float4*)&sCE[(cStrm + 80)*LDK + cQuad*4]
                    : make_float4(0.f,0.f,0.f,0.f);
  __syncthreads();

  // ---- CE pass (final home, small RPT to cap pressure) ----
  cc<6>(encB, Wcomb, true,  0, 24, sSlotNode, sCE, tid);
  cc<6>(encB, Wcomb, true, 24, 24, sSlotNode, sCE, tid);
  cc<6>(encB, Wcomb, true, 48, 24, sSlotNode, sCE, tid);
  cc<6>(encB, Wcomb, true, 72, 18, sSlotNode, sCE, tid);
  __syncthreads();

  // ---- decode: 90 steps, TWO barriers/step.
  //      {A:publish q | B:scores+exp | C:mh + per-head sum (fused)}:
  //      wave-local -> BAR1 -> D: sc+argmax -> BAR2 -> A of next step...
  //      PER-HEAD normalization is REQUIRED (round-8 lesson: it's not a
  //      global scale — dropping it reweights heads). But the head sum is
  //      computed inside C's existing 16-lane butterfly (s_loc rides along),
  //      deleting B's separate 6-stage reduce + the sSum LDS round-trip.
  //      sMh decode layout is SWIZZLED: quad q at float-off (q&7)*16+(q>>3)*4
  //      so D's read (j-th float4 of chunk dkc at j*16+dkc*4) hits 4 distinct
  //      banks instead of 4 addresses on one bank (4-way conflict).
  const int di  = tid >> 2;    // phase D slot
  const int dkc = tid & 3;     // phase D k-chunk
  float visA = 0.f, visB = 0.f, visD = 0.f;

  for (int step = 0; step < STEPS; ++step) {
    // B: scores vs register K; exp (wave-local, pure registers, no reduce)
    float x0, x1;
    {
      const float4 q0 = *(const float4*)&sq[h*16 + 0];
      const float4 q1 = *(const float4*)&sq[h*16 + 4];
      const float4 q2 = *(const float4*)&sq[h*16 + 8];
      const float4 q3 = *(const float4*)&sq[h*16 + 12];
      float s0 = dot4(q0,ka0)+dot4(q1,ka1)+dot4(q2,ka2)+dot4(q3,ka3);
      x0 = expf(s0*0.25f + visA);
      x1 = 0.f;
      if (l < 26) {
        float s1 = dot4(q0,kb0)+dot4(q1,kb1)+dot4(q2,kb2)+dot4(q3,kb3);
        x1 = expf(s1*0.25f + visB);
      }
    }

    // C: mh from register V; att pulled from B's regs via shfl.
    //    s_loc rides the same butterfly -> per-head partition sum for free.
    //    (x1=0 pad in lanes 26..31 reproduces the slot 90..95 zero-pad.)
    {
      const float a0 = __shfl(x0, cStrm);
      const float a1 = __shfl(x0, cStrm + 16);
      const float a2 = __shfl(x0, cStrm + 32);
      const float a3 = __shfl(x0, cStrm + 48);
      const float a4 = __shfl(x1, cStrm);
      const float a5 = __shfl(x1, cStrm + 16);
      float s_loc = (a0+a1)+(a2+a3)+(a4+a5);
      float4 acc = make_float4(0.f,0.f,0.f,0.f);
      fma4(acc, a0, v0);
      fma4(acc, a1, v1);
      fma4(acc, a2, v2);
      fma4(acc, a3, v3);
      fma4(acc, a4, v4);
      fma4(acc, a5, v5);      // v5=0 for cStrm>=10
      #pragma unroll
      for (int off = 1; off < 16; off <<= 1) {
        acc.x += __shfl_xor(acc.x, off);
        acc.y += __shfl_xor(acc.y, off);
        acc.z += __shfl_xor(acc.z, off);
        acc.w += __shfl_xor(acc.w, off);
        s_loc += __shfl_xor(s_loc, off);
      }
      if (cStrm == 0) {
        const float r = 1.0f / s_loc;               // per-head normalization
        float4 o; o.x=acc.x*r; o.y=acc.y*r; o.z=acc.z*r; o.w=acc.w*r;
        *(float4*)&sMh[((cQuad & 7) << 4) + ((cQuad >> 3) << 2)] = o;
      }
    }
    __syncthreads();                               // BAR1: sMh complete

    // Reset NEXT step's argmax buffer. Safe: its last readers (A of step-1)
    // are pre-BAR1; its next writers (D of step+1) are post-BAR2.
    if (tid == NT-1) sPacked[(step+1)&1] = 0ull;

    // D: sc[i] = mh . CE_lds[i]; argmax -> packed atomicMax
    if (tid < 384) {
      float a = 0.f;
      #pragma unroll
      for (int j = 0; j < 8; ++j) {
        const float4 ce = *(const float4*)&sCE[di*LDK + dkc*32 + j*4];
        const float4 mh = *(const float4*)&sMh[j*16 + dkc*4];   // swizzled
        a += dot4(ce, mh);
      }
      a += __shfl_xor(a, 1);
      a += __shfl_xor(a, 2);
      float val = (di < S0) ? a + visD : -INFINITY;
      int   idx = (di < S0) ? di : 127;
      // quad-replicated -> 4 stages (offsets 1,2 would compare identical pairs)
      #pragma unroll
      for (int off = 4; off <= 32; off <<= 1) {
        float ov = __shfl_xor(val, off);
        int   oi = __shfl_xor(idx, off);
        if (ov > val || (ov == val && oi < idx)) { val = ov; idx = oi; }
      }
      if (l == 0) {
        unsigned s = __float_as_uint(val);
        s = (s & 0x80000000u) ? ~s : (s | 0x80000000u);
        unsigned long long pk = ((unsigned long long)s << 32)
                              | (unsigned long long)(unsigned)(127 - idx);
        atomicMax(&sPacked[step&1], pk);
      }
    }
    __syncthreads();                               // BAR2: winner complete

    // A: read winner; write out; update vis; publish next q row (wave-local)
    {
      const unsigned long long u = sPacked[step & 1];
      const int idx = __builtin_amdgcn_readfirstlane(127 - (int)(u & 0xFFull));
      if (tid == 0) out[(size_t)b*N + KL + step] = sSlotNode[idx];
      if (idx == l)      visA = -INFINITY;
      if (idx == l + 64) visB = -INFINITY;
      if (idx == di)     visD = -INFINITY;
      const int want = idx >> 2;                   // wave-uniform (SGPR)
      float qv = qp[0];
      #pragma unroll
      for (int ii = 1; ii < 23; ++ii) qv = (want == ii) ? qp[ii] : qv;
      if (qrg == (idx & 3)) sq[qcol] = qv;
    }
    // no barrier: next B reads sq written by the SAME wave (lgkmcnt-ordered)
  }
}

extern "C" void kernel_launch(void* const* d_in, const int* in_sizes, int n_in,
                              void* d_out, int out_size, void* d_ws, size_t ws_size,
                              hipStream_t stream) {
  // inputs: 0 problems (unused), 1 encoded_nodes f32, 2 Wq_first, 3 Wq_last,
  //         4 Wk, 5 Wv, 6 Wcomb, 7 prefix i32
  const float* enc      = (const float*)d_in[1];
  const float* Wq_first = (const float*)d_in[2];
  const float* Wq_last  = (const float*)d_in[3];
  const float* Wk       = (const float*)d_in[4];
  const float* Wv       = (const float*)d_in[5];
  const float* Wcomb    = (const float*)d_in[6];
  const int*   prefix   = (const int*)d_in[7];
  const int batch = in_sizes[7] / KL;   // 2048
  policy_kernel<<<batch, NT, 0, stream>>>(enc, Wq_first, Wq_last, Wk, Wv, Wcomb,
                                          prefix, (int*)d_out);
}